// Round 1
// baseline (857.365 us; speedup 1.0000x reference)
//
#include <hip/hip_runtime.h>

#define N_NODES 100000
#define NIN 512
#define H1  512
#define H2  128
#define N_EDGES 3200000

typedef __attribute__((ext_vector_type(8))) short bf16x8;
typedef __attribute__((ext_vector_type(4))) float f32x4;

__device__ __forceinline__ unsigned short f2b(float x) {
  union { float f; unsigned int u; } c; c.f = x;
  unsigned int u = c.u;
  unsigned int r = (u + 0x7FFFu + ((u >> 16) & 1u)) >> 16;
  return (unsigned short)r;
}
__device__ __forceinline__ float b2f(unsigned short s) {
  union { unsigned int u; float f; } c; c.u = ((unsigned int)s) << 16;
  return c.f;
}

// ---- prep: W1 [512][512] -> W1t bf16 [n][k]; W2 [512][128] -> W2t bf16 [n][k] ----
__global__ void prep_kernel(const float* __restrict__ W1, const float* __restrict__ W2,
                            unsigned short* __restrict__ W1t, unsigned short* __restrict__ W2t) {
  int idx = blockIdx.x * blockDim.x + threadIdx.x;
  int stride = gridDim.x * blockDim.x;
  for (int i = idx; i < H1 * NIN; i += stride) {
    int n = i >> 9, k = i & 511;
    W1t[i] = f2b(W1[k * H1 + n]);
  }
  for (int i = idx; i < H2 * H1; i += stride) {
    int n = i >> 9, k = i & 511;
    W2t[i] = f2b(W2[k * H2 + n]);
  }
}

__global__ void zero_kernel(float4* __restrict__ p, int n4) {
  int i = blockIdx.x * blockDim.x + threadIdx.x;
  int stride = gridDim.x * blockDim.x;
  float4 z; z.x = 0.f; z.y = 0.f; z.z = 0.f; z.w = 0.f;
  for (; i < n4; i += stride) p[i] = z;
}

// ---- fused MLP: h_a = relu(A@W1+b1)@W2+b2, per 64-row block ----
__global__ __launch_bounds__(512, 2) void mlp_kernel(
    const float* __restrict__ A, const float* __restrict__ b1, const float* __restrict__ b2,
    const unsigned short* __restrict__ W1t, const unsigned short* __restrict__ W2t,
    float* __restrict__ ha_out, unsigned short* __restrict__ ha_bf)
{
  __shared__ __align__(16) unsigned short A_lds[64 * 512];   // 64 KB, swizzled
  __shared__ __align__(16) unsigned short T_lds[64 * 128];   // 16 KB, swizzled

  const int tid  = threadIdx.x;
  const int w    = tid >> 6, lane = tid & 63;
  const int wr   = w & 3;        // row-tile (16 rows)
  const int wc   = w >> 2;       // col-half (64 cols)
  const int l15  = lane & 15, lg = lane >> 4;
  const int row0 = blockIdx.x * 64;

  // ---- stage A block: 64 rows x 512 cols, f32 -> bf16, XOR-swizzled ----
  {
    const int r  = tid >> 3;
    const int cb = (tid & 7) * 4;
    const bool valid = (row0 + r) < N_NODES;
    const float* src = A + (size_t)(row0 + r) * NIN;
    char* dst_row = (char*)A_lds + r * 1024;
    const int swz = (r & 7) << 4;
    #pragma unroll
    for (int ki = 0; ki < NIN; ki += 32) {
      int k = cb + ki;
      float x0 = 0.f, x1 = 0.f, x2 = 0.f, x3 = 0.f;
      if (valid) { const float4 v = *(const float4*)(src + k); x0 = v.x; x1 = v.y; x2 = v.z; x3 = v.w; }
      uint2 p;
      p.x = (unsigned)f2b(x0) | ((unsigned)f2b(x1) << 16);
      p.y = (unsigned)f2b(x2) | ((unsigned)f2b(x3) << 16);
      *(uint2*)(dst_row + ((k * 2) ^ swz)) = p;
    }
  }
  __syncthreads();

  f32x4 acc_ha[4];
  #pragma unroll
  for (int i = 0; i < 4; ++i) acc_ha[i] = (f32x4){0.f, 0.f, 0.f, 0.f};

  const int ar = wr * 16 + l15;
  const int swzA = (ar & 7) << 4;
  const char* arow = (const char*)A_lds + ar * 1024;
  const char* trow = (const char*)T_lds + ar * 256;

  for (int nc = 0; nc < 4; ++nc) {
    // ---- GEMM1: T = A @ W1[:, chunk], K = 512 ----
    f32x4 accT[4];
    #pragma unroll
    for (int i = 0; i < 4; ++i) accT[i] = (f32x4){0.f, 0.f, 0.f, 0.f};

    #pragma unroll 4
    for (int ks = 0; ks < NIN; ks += 32) {
      int ak = ks + lg * 8;
      bf16x8 af = *(const bf16x8*)(arow + ((ak * 2) ^ swzA));
      #pragma unroll
      for (int ct = 0; ct < 4; ++ct) {
        int n = nc * 128 + wc * 64 + ct * 16 + l15;
        bf16x8 bf = *(const bf16x8*)(W1t + n * NIN + ak);
        accT[ct] = __builtin_amdgcn_mfma_f32_16x16x32_bf16(af, bf, accT[ct], 0, 0, 0);
      }
    }

    __syncthreads();   // previous chunk's GEMM2 reads of T_lds done
    // ---- bias + relu, write T chunk to LDS as bf16 (swizzled) ----
    #pragma unroll
    for (int ct = 0; ct < 4; ++ct) {
      int col = wc * 64 + ct * 16 + l15;
      float bias = b1[nc * 128 + col];
      #pragma unroll
      for (int q = 0; q < 4; ++q) {
        float v = accT[ct][q] + bias;
        v = v > 0.f ? v : 0.f;
        int r = wr * 16 + lg * 4 + q;
        *(unsigned short*)((char*)T_lds + r * 256 + ((col * 2) ^ ((r & 7) << 4))) = f2b(v);
      }
    }
    __syncthreads();

    // ---- GEMM2 partial: h_a += T_chunk @ W2[chunk, :], K = 128 ----
    #pragma unroll
    for (int ks = 0; ks < 128; ks += 32) {
      int ak = ks + lg * 8;
      bf16x8 af = *(const bf16x8*)(trow + ((ak * 2) ^ swzA));
      #pragma unroll
      for (int ct = 0; ct < 4; ++ct) {
        int n = wc * 64 + ct * 16 + l15;
        bf16x8 bf = *(const bf16x8*)(W2t + n * H1 + nc * 128 + ak);
        acc_ha[ct] = __builtin_amdgcn_mfma_f32_16x16x32_bf16(af, bf, acc_ha[ct], 0, 0, 0);
      }
    }
  }

  // ---- epilogue: + b2, write f32 h_a and bf16 gather copy ----
  #pragma unroll
  for (int ct = 0; ct < 4; ++ct) {
    int col = wc * 64 + ct * 16 + l15;
    float bias = b2[col];
    #pragma unroll
    for (int q = 0; q < 4; ++q) {
      int r = row0 + wr * 16 + lg * 4 + q;
      if (r < N_NODES) {
        float v = acc_ha[ct][q] + bias;
        ha_out[(size_t)r * H2 + col] = v;
        ha_bf[(size_t)r * H2 + col] = f2b(v);
      }
    }
  }
}

// ---- aggregation: h_p[r] += vals[e] * h_a[cols[e]], rows sorted ----
__global__ __launch_bounds__(256) void agg_kernel(
    const int* __restrict__ rows, const int* __restrict__ cols, const float* __restrict__ vals,
    const unsigned short* __restrict__ ha_bf, float* __restrict__ hp)
{
  const int lane = threadIdx.x & 63;
  const int gw = (blockIdx.x * blockDim.x + threadIdx.x) >> 6;
  const int nw = (gridDim.x * blockDim.x) >> 6;
  const int epw = (N_EDGES + nw - 1) / nw;
  int e0 = gw * epw;
  int e1 = e0 + epw; if (e1 > N_EDGES) e1 = N_EDGES;
  if (e0 >= N_EDGES) return;

  float acc0 = 0.f, acc1 = 0.f;
  int cur = rows[e0];
  for (int e = e0; e < e1; ++e) {
    int r = rows[e];
    int c = cols[e];
    float v = vals[e];
    unsigned int u = *(const unsigned int*)(ha_bf + ((size_t)c << 7) + lane * 2);
    if (r != cur) {
      atomicAdd(&hp[((size_t)cur << 7) + lane * 2], acc0);
      atomicAdd(&hp[((size_t)cur << 7) + lane * 2 + 1], acc1);
      acc0 = 0.f; acc1 = 0.f;
      cur = r;
    }
    acc0 = fmaf(v, b2f((unsigned short)(u & 0xffffu)), acc0);
    acc1 = fmaf(v, b2f((unsigned short)(u >> 16)), acc1);
  }
  atomicAdd(&hp[((size_t)cur << 7) + lane * 2], acc0);
  atomicAdd(&hp[((size_t)cur << 7) + lane * 2 + 1], acc1);
}

extern "C" void kernel_launch(void* const* d_in, const int* in_sizes, int n_in,
                              void* d_out, int out_size, void* d_ws, size_t ws_size,
                              hipStream_t stream) {
  const float* seq_a   = (const float*)d_in[0];
  const float* W1      = (const float*)d_in[1];
  const float* b1      = (const float*)d_in[2];
  const float* W2      = (const float*)d_in[3];
  const float* b2      = (const float*)d_in[4];
  const int*   adj_rows = (const int*)d_in[5];
  const int*   adj_cols = (const int*)d_in[6];
  const float* adj_vals = (const float*)d_in[7];

  unsigned short* W1t   = (unsigned short*)d_ws;        // 512*512 bf16
  unsigned short* W2t   = W1t + H1 * NIN;               // 128*512 bf16
  unsigned short* ha_bf = W2t + H2 * H1;                // 100000*128 bf16

  float* ha_out = (float*)d_out;
  float* hp     = ha_out + (size_t)N_NODES * H2;

  prep_kernel<<<640, 256, 0, stream>>>(W1, W2, W1t, W2t);
  zero_kernel<<<2048, 256, 0, stream>>>((float4*)hp, (N_NODES * H2) / 4);
  mlp_kernel<<<(N_NODES + 63) / 64, 512, 0, stream>>>(seq_a, b1, b2, W1t, W2t, ha_out, ha_bf);
  agg_kernel<<<2048, 256, 0, stream>>>(adj_rows, adj_cols, adj_vals, ha_bf, hp);
}

// Round 2
// 561.794 us; speedup vs baseline: 1.5261x; 1.5261x over previous
//
#include <hip/hip_runtime.h>

#define N_NODES 100000
#define ROWS_PAD 100096
#define NIN 512
#define H1  512
#define H2  128
#define N_EDGES 3200000

typedef __attribute__((ext_vector_type(8))) short bf16x8;
typedef __attribute__((ext_vector_type(4))) float f32x4;

__device__ __forceinline__ unsigned short f2b(float x) {
  union { float f; unsigned int u; } c; c.f = x;
  unsigned int u = c.u;
  unsigned int r = (u + 0x7FFFu + ((u >> 16) & 1u)) >> 16;
  return (unsigned short)r;
}
__device__ __forceinline__ float b2f(unsigned short s) {
  union { unsigned int u; float f; } c; c.u = ((unsigned int)s) << 16;
  return c.f;
}

typedef const __attribute__((address_space(1))) unsigned int* gp1_t;
typedef __attribute__((address_space(3))) unsigned int* sp3_t;
__device__ __forceinline__ void gl_lds16(const void* g, void* s) {
  __builtin_amdgcn_global_load_lds((gp1_t)g, (sp3_t)s, 16, 0, 0);
}

// ---- prep_a: seq_a f32 [N][512] -> A1 bf16 pre-swizzled: A1[n][k] = bf16(A[n][k ^ ((n&7)<<3)]) ----
__global__ void prep_a_kernel(const float* __restrict__ A, unsigned short* __restrict__ A1) {
  int idx = blockIdx.x * blockDim.x + threadIdx.x;
  int stride = gridDim.x * blockDim.x;
  for (int i = idx; i < N_NODES * 64; i += stride) {
    int n = i >> 6;
    int kb = (i & 63) << 3;
    int ks = kb ^ ((n & 7) << 3);
    const float* src = A + ((size_t)n << 9) + ks;
    float4 v0 = *(const float4*)src;
    float4 v1 = *(const float4*)(src + 4);
    uint4 p;
    p.x = (unsigned)f2b(v0.x) | ((unsigned)f2b(v0.y) << 16);
    p.y = (unsigned)f2b(v0.z) | ((unsigned)f2b(v0.w) << 16);
    p.z = (unsigned)f2b(v1.x) | ((unsigned)f2b(v1.y) << 16);
    p.w = (unsigned)f2b(v1.z) | ((unsigned)f2b(v1.w) << 16);
    *(uint4*)(A1 + ((size_t)n << 9) + kb) = p;
  }
}

// ---- prep_w: W1[k][n] -> W1t[n][k] bf16 pre-swizzled; same for W2 ----
__global__ void prep_w_kernel(const float* __restrict__ W1, const float* __restrict__ W2,
                              unsigned short* __restrict__ W1t, unsigned short* __restrict__ W2t) {
  int idx = blockIdx.x * blockDim.x + threadIdx.x;
  int stride = gridDim.x * blockDim.x;
  for (int i = idx; i < H1 * NIN; i += stride) {
    int n = i >> 9, k = i & 511;
    W1t[i] = f2b(W1[(size_t)(k ^ ((n & 7) << 3)) * H1 + n]);
  }
  for (int i = idx; i < H2 * H1; i += stride) {
    int n = i >> 9, k = i & 511;
    W2t[i] = f2b(W2[(size_t)(k ^ ((n & 7) << 3)) * H2 + n]);
  }
}

__global__ void zero_kernel(float4* __restrict__ p, int n4) {
  int i = blockIdx.x * blockDim.x + threadIdx.x;
  int stride = gridDim.x * blockDim.x;
  float4 z; z.x = 0.f; z.y = 0.f; z.z = 0.f; z.w = 0.f;
  for (; i < n4; i += stride) p[i] = z;
}

// ---- GEMM1: h_pre = relu(A1 @ W1t^T + b1), 128x128 tile, BK=64, m97 structure ----
__global__ __launch_bounds__(256, 4) void gemm1_kernel(
    const unsigned short* __restrict__ A1, const unsigned short* __restrict__ W1t,
    const float* __restrict__ b1, unsigned short* __restrict__ h_pre)
{
  __shared__ __align__(16) unsigned short Asm[128 * 64];
  __shared__ __align__(16) unsigned short Bsm[128 * 64];
  const int tid = threadIdx.x;
  const int w = tid >> 6, lane = tid & 63;
  const int l15 = lane & 15, lg = lane >> 4;
  const int wr = w & 1, wc = w >> 1;
  const int row0 = blockIdx.y * 128;
  const int n0 = blockIdx.x * 128;

  f32x4 acc[4][4];
  #pragma unroll
  for (int m = 0; m < 4; ++m)
    #pragma unroll
    for (int n = 0; n < 4; ++n) acc[m][n] = (f32x4){0.f, 0.f, 0.f, 0.f};

  const int so = w * 1024 + lane * 16;
  for (int kt = 0; kt < 8; ++kt) {
    #pragma unroll
    for (int it = 0; it < 4; ++it) {
      int o = it * 4096 + so;
      int r = o >> 7, kb = o & 127;
      gl_lds16((const char*)A1 + (((size_t)(row0 + r)) << 10) + (kt << 7) + kb, (char*)Asm + o);
      gl_lds16((const char*)W1t + (((size_t)(n0 + r)) << 10) + (kt << 7) + kb, (char*)Bsm + o);
    }
    __syncthreads();
    #pragma unroll
    for (int ks = 0; ks < 2; ++ks) {
      bf16x8 af[4], bfr[4];
      #pragma unroll
      for (int m = 0; m < 4; ++m) {
        int r = wr * 64 + m * 16 + l15;
        af[m] = *(const bf16x8*)((const char*)Asm + (r << 7) + (((ks << 6) + (lg << 4)) ^ ((r & 7) << 4)));
      }
      #pragma unroll
      for (int n = 0; n < 4; ++n) {
        int r = wc * 64 + n * 16 + l15;
        bfr[n] = *(const bf16x8*)((const char*)Bsm + (r << 7) + (((ks << 6) + (lg << 4)) ^ ((r & 7) << 4)));
      }
      #pragma unroll
      for (int m = 0; m < 4; ++m)
        #pragma unroll
        for (int n = 0; n < 4; ++n)
          acc[m][n] = __builtin_amdgcn_mfma_f32_16x16x32_bf16(af[m], bfr[n], acc[m][n], 0, 0, 0);
    }
    __syncthreads();
  }

  #pragma unroll
  for (int n = 0; n < 4; ++n) {
    int col = n0 + wc * 64 + n * 16 + l15;
    float bias = b1[col];
    #pragma unroll
    for (int m = 0; m < 4; ++m) {
      #pragma unroll
      for (int q = 0; q < 4; ++q) {
        int row = row0 + wr * 64 + m * 16 + lg * 4 + q;
        if (row < N_NODES) {
          float v = acc[m][n][q] + bias;
          v = v > 0.f ? v : 0.f;
          h_pre[((size_t)row << 9) + (col ^ ((row & 7) << 3))] = f2b(v);
        }
      }
    }
  }
}

// ---- GEMM2: ha = h_pre @ W2t^T + b2 -> f32 d_out + bf16 ws copy ----
__global__ __launch_bounds__(256, 4) void gemm2_kernel(
    const unsigned short* __restrict__ Hp, const unsigned short* __restrict__ W2t,
    const float* __restrict__ b2, float* __restrict__ ha_out, unsigned short* __restrict__ ha_bf)
{
  __shared__ __align__(16) unsigned short Asm[128 * 64];
  __shared__ __align__(16) unsigned short Bsm[128 * 64];
  const int tid = threadIdx.x;
  const int w = tid >> 6, lane = tid & 63;
  const int l15 = lane & 15, lg = lane >> 4;
  const int wr = w & 1, wc = w >> 1;
  const int row0 = blockIdx.y * 128;

  f32x4 acc[4][4];
  #pragma unroll
  for (int m = 0; m < 4; ++m)
    #pragma unroll
    for (int n = 0; n < 4; ++n) acc[m][n] = (f32x4){0.f, 0.f, 0.f, 0.f};

  const int so = w * 1024 + lane * 16;
  for (int kt = 0; kt < 8; ++kt) {
    #pragma unroll
    for (int it = 0; it < 4; ++it) {
      int o = it * 4096 + so;
      int r = o >> 7, kb = o & 127;
      gl_lds16((const char*)Hp + (((size_t)(row0 + r)) << 10) + (kt << 7) + kb, (char*)Asm + o);
      gl_lds16((const char*)W2t + (((size_t)r) << 10) + (kt << 7) + kb, (char*)Bsm + o);
    }
    __syncthreads();
    #pragma unroll
    for (int ks = 0; ks < 2; ++ks) {
      bf16x8 af[4], bfr[4];
      #pragma unroll
      for (int m = 0; m < 4; ++m) {
        int r = wr * 64 + m * 16 + l15;
        af[m] = *(const bf16x8*)((const char*)Asm + (r << 7) + (((ks << 6) + (lg << 4)) ^ ((r & 7) << 4)));
      }
      #pragma unroll
      for (int n = 0; n < 4; ++n) {
        int r = wc * 64 + n * 16 + l15;
        bfr[n] = *(const bf16x8*)((const char*)Bsm + (r << 7) + (((ks << 6) + (lg << 4)) ^ ((r & 7) << 4)));
      }
      #pragma unroll
      for (int m = 0; m < 4; ++m)
        #pragma unroll
        for (int n = 0; n < 4; ++n)
          acc[m][n] = __builtin_amdgcn_mfma_f32_16x16x32_bf16(af[m], bfr[n], acc[m][n], 0, 0, 0);
    }
    __syncthreads();
  }

  #pragma unroll
  for (int n = 0; n < 4; ++n) {
    int col = wc * 64 + n * 16 + l15;
    float bias = b2[col];
    #pragma unroll
    for (int m = 0; m < 4; ++m) {
      #pragma unroll
      for (int q = 0; q < 4; ++q) {
        int row = row0 + wr * 64 + m * 16 + lg * 4 + q;
        if (row < N_NODES) {
          float v = acc[m][n][q] + bias;
          ha_out[((size_t)row << 7) + col] = v;
          ha_bf[((size_t)row << 7) + col] = f2b(v);
        }
      }
    }
  }
}

// ---- aggregation: h_p[r] += vals[e] * h_a[cols[e]], rows sorted ----
__global__ __launch_bounds__(256) void agg_kernel(
    const int* __restrict__ rows, const int* __restrict__ cols, const float* __restrict__ vals,
    const unsigned short* __restrict__ ha_bf, float* __restrict__ hp)
{
  const int lane = threadIdx.x & 63;
  const int gw = (blockIdx.x * blockDim.x + threadIdx.x) >> 6;
  const int nw = (gridDim.x * blockDim.x) >> 6;
  const int epw = (N_EDGES + nw - 1) / nw;
  int e0 = gw * epw;
  int e1 = e0 + epw; if (e1 > N_EDGES) e1 = N_EDGES;
  if (e0 >= N_EDGES) return;

  float acc0 = 0.f, acc1 = 0.f;
  int cur = rows[e0];
  for (int e = e0; e < e1; ++e) {
    int r = rows[e];
    int c = cols[e];
    float v = vals[e];
    unsigned int u = *(const unsigned int*)(ha_bf + ((size_t)c << 7) + lane * 2);
    if (r != cur) {
      atomicAdd(&hp[((size_t)cur << 7) + lane * 2], acc0);
      atomicAdd(&hp[((size_t)cur << 7) + lane * 2 + 1], acc1);
      acc0 = 0.f; acc1 = 0.f;
      cur = r;
    }
    acc0 = fmaf(v, b2f((unsigned short)(u & 0xffffu)), acc0);
    acc1 = fmaf(v, b2f((unsigned short)(u >> 16)), acc1);
  }
  atomicAdd(&hp[((size_t)cur << 7) + lane * 2], acc0);
  atomicAdd(&hp[((size_t)cur << 7) + lane * 2 + 1], acc1);
}

extern "C" void kernel_launch(void* const* d_in, const int* in_sizes, int n_in,
                              void* d_out, int out_size, void* d_ws, size_t ws_size,
                              hipStream_t stream) {
  const float* seq_a    = (const float*)d_in[0];
  const float* W1       = (const float*)d_in[1];
  const float* b1       = (const float*)d_in[2];
  const float* W2       = (const float*)d_in[3];
  const float* b2       = (const float*)d_in[4];
  const int*   adj_rows = (const int*)d_in[5];
  const int*   adj_cols = (const int*)d_in[6];
  const float* adj_vals = (const float*)d_in[7];

  unsigned short* A1    = (unsigned short*)d_ws;            // ROWS_PAD x 512
  unsigned short* h_pre = A1 + (size_t)ROWS_PAD * NIN;      // ROWS_PAD x 512
  unsigned short* W1t   = h_pre + (size_t)ROWS_PAD * H1;    // 512 x 512
  unsigned short* W2t   = W1t + (size_t)H1 * NIN;           // 128 x 512
  unsigned short* ha_bf = W2t + (size_t)H2 * H1;            // N_NODES x 128

  float* ha_out = (float*)d_out;
  float* hp     = ha_out + (size_t)N_NODES * H2;

  prep_a_kernel<<<2048, 256, 0, stream>>>(seq_a, A1);
  prep_w_kernel<<<1280, 256, 0, stream>>>(W1, W2, W1t, W2t);
  zero_kernel<<<2048, 256, 0, stream>>>((float4*)hp, (N_NODES * H2) / 4);
  gemm1_kernel<<<dim3(4, 782), 256, 0, stream>>>(A1, W1t, b1, h_pre);
  gemm2_kernel<<<dim3(1, 782), 256, 0, stream>>>(h_pre, W2t, b2, ha_out, ha_bf);
  agg_kernel<<<2048, 256, 0, stream>>>(adj_rows, adj_cols, adj_vals, ha_bf, hp);
}

// Round 3
// 390.637 us; speedup vs baseline: 2.1948x; 1.4381x over previous
//
#include <hip/hip_runtime.h>

#define N_NODES 100000
#define ROWS_PAD 100096
#define NIN 512
#define H1  512
#define H2  128
#define N_EDGES 3200000

typedef __attribute__((ext_vector_type(8))) short bf16x8;
typedef __attribute__((ext_vector_type(4))) float f32x4;

__device__ __forceinline__ unsigned short f2b(float x) {
  union { float f; unsigned int u; } c; c.f = x;
  unsigned int u = c.u;
  unsigned int r = (u + 0x7FFFu + ((u >> 16) & 1u)) >> 16;
  return (unsigned short)r;
}
// low/high bf16 of a packed uint -> f32 (1 VALU op each)
__device__ __forceinline__ float blo(unsigned u) {
  union { unsigned x; float f; } c; c.x = u << 16; return c.f;
}
__device__ __forceinline__ float bhi(unsigned u) {
  union { unsigned x; float f; } c; c.x = u & 0xffff0000u; return c.f;
}

typedef const __attribute__((address_space(1))) unsigned int* gp1_t;
typedef __attribute__((address_space(3))) unsigned int* sp3_t;
__device__ __forceinline__ void gl_lds16(const void* g, void* s) {
  __builtin_amdgcn_global_load_lds((gp1_t)g, (sp3_t)s, 16, 0, 0);
}

// ---- prep_a: seq_a f32 [N][512] -> A1 bf16 pre-swizzled: A1[n][k] = bf16(A[n][k ^ ((n&7)<<3)]) ----
__global__ void prep_a_kernel(const float* __restrict__ A, unsigned short* __restrict__ A1) {
  int idx = blockIdx.x * blockDim.x + threadIdx.x;
  int stride = gridDim.x * blockDim.x;
  for (int i = idx; i < N_NODES * 64; i += stride) {
    int n = i >> 6;
    int kb = (i & 63) << 3;
    int ks = kb ^ ((n & 7) << 3);
    const float* src = A + ((size_t)n << 9) + ks;
    float4 v0 = *(const float4*)src;
    float4 v1 = *(const float4*)(src + 4);
    uint4 p;
    p.x = (unsigned)f2b(v0.x) | ((unsigned)f2b(v0.y) << 16);
    p.y = (unsigned)f2b(v0.z) | ((unsigned)f2b(v0.w) << 16);
    p.z = (unsigned)f2b(v1.x) | ((unsigned)f2b(v1.y) << 16);
    p.w = (unsigned)f2b(v1.z) | ((unsigned)f2b(v1.w) << 16);
    *(uint4*)(A1 + ((size_t)n << 9) + kb) = p;
  }
}

// ---- prep_w: W1[k][n] -> W1t[n][k] bf16 pre-swizzled; same for W2 ----
__global__ void prep_w_kernel(const float* __restrict__ W1, const float* __restrict__ W2,
                              unsigned short* __restrict__ W1t, unsigned short* __restrict__ W2t) {
  int idx = blockIdx.x * blockDim.x + threadIdx.x;
  int stride = gridDim.x * blockDim.x;
  for (int i = idx; i < H1 * NIN; i += stride) {
    int n = i >> 9, k = i & 511;
    W1t[i] = f2b(W1[(size_t)(k ^ ((n & 7) << 3)) * H1 + n]);
  }
  for (int i = idx; i < H2 * H1; i += stride) {
    int n = i >> 9, k = i & 511;
    W2t[i] = f2b(W2[(size_t)(k ^ ((n & 7) << 3)) * H2 + n]);
  }
}

__global__ void zero_kernel(float4* __restrict__ p, int n4) {
  int i = blockIdx.x * blockDim.x + threadIdx.x;
  int stride = gridDim.x * blockDim.x;
  float4 z; z.x = 0.f; z.y = 0.f; z.z = 0.f; z.w = 0.f;
  for (; i < n4; i += stride) p[i] = z;
}

// ---- GEMM1: h_pre = relu(A1 @ W1t^T + b1), 128x128 tile, BK=64, m97 structure ----
__global__ __launch_bounds__(256, 4) void gemm1_kernel(
    const unsigned short* __restrict__ A1, const unsigned short* __restrict__ W1t,
    const float* __restrict__ b1, unsigned short* __restrict__ h_pre)
{
  __shared__ __align__(16) unsigned short Asm[128 * 64];
  __shared__ __align__(16) unsigned short Bsm[128 * 64];
  const int tid = threadIdx.x;
  const int w = tid >> 6, lane = tid & 63;
  const int l15 = lane & 15, lg = lane >> 4;
  const int wr = w & 1, wc = w >> 1;
  const int row0 = blockIdx.y * 128;
  const int n0 = blockIdx.x * 128;

  f32x4 acc[4][4];
  #pragma unroll
  for (int m = 0; m < 4; ++m)
    #pragma unroll
    for (int n = 0; n < 4; ++n) acc[m][n] = (f32x4){0.f, 0.f, 0.f, 0.f};

  const int so = w * 1024 + lane * 16;
  for (int kt = 0; kt < 8; ++kt) {
    #pragma unroll
    for (int it = 0; it < 4; ++it) {
      int o = it * 4096 + so;
      int r = o >> 7, kb = o & 127;
      gl_lds16((const char*)A1 + (((size_t)(row0 + r)) << 10) + (kt << 7) + kb, (char*)Asm + o);
      gl_lds16((const char*)W1t + (((size_t)(n0 + r)) << 10) + (kt << 7) + kb, (char*)Bsm + o);
    }
    __syncthreads();
    #pragma unroll
    for (int ks = 0; ks < 2; ++ks) {
      bf16x8 af[4], bfr[4];
      #pragma unroll
      for (int m = 0; m < 4; ++m) {
        int r = wr * 64 + m * 16 + l15;
        af[m] = *(const bf16x8*)((const char*)Asm + (r << 7) + (((ks << 6) + (lg << 4)) ^ ((r & 7) << 4)));
      }
      #pragma unroll
      for (int n = 0; n < 4; ++n) {
        int r = wc * 64 + n * 16 + l15;
        bfr[n] = *(const bf16x8*)((const char*)Bsm + (r << 7) + (((ks << 6) + (lg << 4)) ^ ((r & 7) << 4)));
      }
      #pragma unroll
      for (int m = 0; m < 4; ++m)
        #pragma unroll
        for (int n = 0; n < 4; ++n)
          acc[m][n] = __builtin_amdgcn_mfma_f32_16x16x32_bf16(af[m], bfr[n], acc[m][n], 0, 0, 0);
    }
    __syncthreads();
  }

  #pragma unroll
  for (int n = 0; n < 4; ++n) {
    int col = n0 + wc * 64 + n * 16 + l15;
    float bias = b1[col];
    #pragma unroll
    for (int m = 0; m < 4; ++m) {
      #pragma unroll
      for (int q = 0; q < 4; ++q) {
        int row = row0 + wr * 64 + m * 16 + lg * 4 + q;
        if (row < N_NODES) {
          float v = acc[m][n][q] + bias;
          v = v > 0.f ? v : 0.f;
          h_pre[((size_t)row << 9) + (col ^ ((row & 7) << 3))] = f2b(v);
        }
      }
    }
  }
}

// ---- GEMM2: ha = h_pre @ W2t^T + b2 -> f32 d_out + bf16 ws copy ----
__global__ __launch_bounds__(256, 4) void gemm2_kernel(
    const unsigned short* __restrict__ Hp, const unsigned short* __restrict__ W2t,
    const float* __restrict__ b2, float* __restrict__ ha_out, unsigned short* __restrict__ ha_bf)
{
  __shared__ __align__(16) unsigned short Asm[128 * 64];
  __shared__ __align__(16) unsigned short Bsm[128 * 64];
  const int tid = threadIdx.x;
  const int w = tid >> 6, lane = tid & 63;
  const int l15 = lane & 15, lg = lane >> 4;
  const int wr = w & 1, wc = w >> 1;
  const int row0 = blockIdx.y * 128;

  f32x4 acc[4][4];
  #pragma unroll
  for (int m = 0; m < 4; ++m)
    #pragma unroll
    for (int n = 0; n < 4; ++n) acc[m][n] = (f32x4){0.f, 0.f, 0.f, 0.f};

  const int so = w * 1024 + lane * 16;
  for (int kt = 0; kt < 8; ++kt) {
    #pragma unroll
    for (int it = 0; it < 4; ++it) {
      int o = it * 4096 + so;
      int r = o >> 7, kb = o & 127;
      gl_lds16((const char*)Hp + (((size_t)(row0 + r)) << 10) + (kt << 7) + kb, (char*)Asm + o);
      gl_lds16((const char*)W2t + (((size_t)r) << 10) + (kt << 7) + kb, (char*)Bsm + o);
    }
    __syncthreads();
    #pragma unroll
    for (int ks = 0; ks < 2; ++ks) {
      bf16x8 af[4], bfr[4];
      #pragma unroll
      for (int m = 0; m < 4; ++m) {
        int r = wr * 64 + m * 16 + l15;
        af[m] = *(const bf16x8*)((const char*)Asm + (r << 7) + (((ks << 6) + (lg << 4)) ^ ((r & 7) << 4)));
      }
      #pragma unroll
      for (int n = 0; n < 4; ++n) {
        int r = wc * 64 + n * 16 + l15;
        bfr[n] = *(const bf16x8*)((const char*)Bsm + (r << 7) + (((ks << 6) + (lg << 4)) ^ ((r & 7) << 4)));
      }
      #pragma unroll
      for (int m = 0; m < 4; ++m)
        #pragma unroll
        for (int n = 0; n < 4; ++n)
          acc[m][n] = __builtin_amdgcn_mfma_f32_16x16x32_bf16(af[m], bfr[n], acc[m][n], 0, 0, 0);
    }
    __syncthreads();
  }

  #pragma unroll
  for (int n = 0; n < 4; ++n) {
    int col = wc * 64 + n * 16 + l15;
    float bias = b2[col];
    #pragma unroll
    for (int m = 0; m < 4; ++m) {
      #pragma unroll
      for (int q = 0; q < 4; ++q) {
        int row = row0 + wr * 64 + m * 16 + lg * 4 + q;
        if (row < N_NODES) {
          float v = acc[m][n][q] + bias;
          ha_out[((size_t)row << 7) + col] = v;
          ha_bf[((size_t)row << 7) + col] = f2b(v);
        }
      }
    }
  }
}

// ---- aggregation v2: 8-edge groups, 8 gathers in flight, atomic-elision ----
__global__ __launch_bounds__(256) void agg_kernel(
    const int* __restrict__ rows, const int* __restrict__ cols, const float* __restrict__ vals,
    const unsigned short* __restrict__ ha_bf, float* __restrict__ hp)
{
  const int lane = threadIdx.x & 63;
  const int gw = (blockIdx.x * blockDim.x + threadIdx.x) >> 6;
  const int nw = (gridDim.x * blockDim.x) >> 6;
  int epw = (N_EDGES + nw - 1) / nw;
  epw = (epw + 7) & ~7;                       // keep int4 alignment
  int e0 = gw * epw;
  if (e0 >= N_EDGES) return;
  int e1 = e0 + epw; if (e1 > N_EDGES) e1 = N_EDGES;
  const int ef = e0 + ((e1 - e0) & ~7);

  const unsigned* gtab = (const unsigned*)ha_bf;   // [node][64] packed bf16 pairs

  float acc0 = 0.f, acc1 = 0.f;
  int cur = rows[e0];
  bool first = true;                               // first flushed row may be shared with prev wave

  // flush current row; interior rows are exclusively owned -> plain store
  auto flushrow = [&](int rr) {
    float* p = &hp[((size_t)cur << 7) + (lane << 1)];
    if (first) { atomicAdd(p, acc0); atomicAdd(p + 1, acc1); first = false; }
    else       { float2 st; st.x = acc0; st.y = acc1; *(float2*)p = st; }
    acc0 = 0.f; acc1 = 0.f; cur = rr;
  };
  auto edge = [&](int rr, float vv, unsigned gg) {
    if (rr != cur) flushrow(rr);
    acc0 = fmaf(vv, blo(gg), acc0);
    acc1 = fmaf(vv, bhi(gg), acc1);
  };

  for (int e = e0; e < ef; e += 8) {
    int4   ra = *(const int4*)(rows + e);
    int4   rb = *(const int4*)(rows + e + 4);
    int4   ca = *(const int4*)(cols + e);
    int4   cb = *(const int4*)(cols + e + 4);
    float4 va = *(const float4*)(vals + e);
    float4 vb = *(const float4*)(vals + e + 4);
    // 8 independent gathers in flight
    unsigned g0 = gtab[((size_t)ca.x << 6) + lane];
    unsigned g1 = gtab[((size_t)ca.y << 6) + lane];
    unsigned g2 = gtab[((size_t)ca.z << 6) + lane];
    unsigned g3 = gtab[((size_t)ca.w << 6) + lane];
    unsigned g4 = gtab[((size_t)cb.x << 6) + lane];
    unsigned g5 = gtab[((size_t)cb.y << 6) + lane];
    unsigned g6 = gtab[((size_t)cb.z << 6) + lane];
    unsigned g7 = gtab[((size_t)cb.w << 6) + lane];
    if ((ra.x == cur) && (rb.w == cur)) {          // whole group in current row (~75%)
      float p0 = fmaf(va.x, blo(g0), fmaf(va.z, blo(g2), fmaf(vb.x, blo(g4), fmaf(vb.z, blo(g6), acc0))));
      float q0 = fmaf(va.y, blo(g1), fmaf(va.w, blo(g3), fmaf(vb.y, blo(g5), fmaf(vb.w, blo(g7), 0.f))));
      acc0 = p0 + q0;
      float p1 = fmaf(va.x, bhi(g0), fmaf(va.z, bhi(g2), fmaf(vb.x, bhi(g4), fmaf(vb.z, bhi(g6), acc1))));
      float q1 = fmaf(va.y, bhi(g1), fmaf(va.w, bhi(g3), fmaf(vb.y, bhi(g5), fmaf(vb.w, bhi(g7), 0.f))));
      acc1 = p1 + q1;
    } else {
      edge(ra.x, va.x, g0); edge(ra.y, va.y, g1);
      edge(ra.z, va.z, g2); edge(ra.w, va.w, g3);
      edge(rb.x, vb.x, g4); edge(rb.y, vb.y, g5);
      edge(rb.z, vb.z, g6); edge(rb.w, vb.w, g7);
    }
  }
  for (int e = ef; e < e1; ++e) {
    unsigned g = gtab[((size_t)cols[e] << 6) + lane];
    edge(rows[e], vals[e], g);
  }
  // last row may continue into next wave's chunk -> atomic
  atomicAdd(&hp[((size_t)cur << 7) + (lane << 1)], acc0);
  atomicAdd(&hp[((size_t)cur << 7) + (lane << 1) + 1], acc1);
}

extern "C" void kernel_launch(void* const* d_in, const int* in_sizes, int n_in,
                              void* d_out, int out_size, void* d_ws, size_t ws_size,
                              hipStream_t stream) {
  const float* seq_a    = (const float*)d_in[0];
  const float* W1       = (const float*)d_in[1];
  const float* b1       = (const float*)d_in[2];
  const float* W2       = (const float*)d_in[3];
  const float* b2       = (const float*)d_in[4];
  const int*   adj_rows = (const int*)d_in[5];
  const int*   adj_cols = (const int*)d_in[6];
  const float* adj_vals = (const float*)d_in[7];

  unsigned short* A1    = (unsigned short*)d_ws;            // ROWS_PAD x 512
  unsigned short* h_pre = A1 + (size_t)ROWS_PAD * NIN;      // ROWS_PAD x 512
  unsigned short* W1t   = h_pre + (size_t)ROWS_PAD * H1;    // 512 x 512
  unsigned short* W2t   = W1t + (size_t)H1 * NIN;           // 128 x 512
  unsigned short* ha_bf = W2t + (size_t)H2 * H1;            // N_NODES x 128

  float* ha_out = (float*)d_out;
  float* hp     = ha_out + (size_t)N_NODES * H2;

  prep_a_kernel<<<2048, 256, 0, stream>>>(seq_a, A1);
  prep_w_kernel<<<1280, 256, 0, stream>>>(W1, W2, W1t, W2t);
  zero_kernel<<<2048, 256, 0, stream>>>((float4*)hp, (N_NODES * H2) / 4);
  gemm1_kernel<<<dim3(4, 782), 256, 0, stream>>>(A1, W1t, b1, h_pre);
  gemm2_kernel<<<dim3(1, 782), 256, 0, stream>>>(h_pre, W2t, b2, ha_out, ha_bf);
  agg_kernel<<<2048, 256, 0, stream>>>(adj_rows, adj_cols, adj_vals, ha_bf, hp);
}

// Round 4
// 367.100 us; speedup vs baseline: 2.3355x; 1.0641x over previous
//
#include <hip/hip_runtime.h>

#define N_NODES 100000
#define ROWS_PAD 100096
#define NIN 512
#define H1  512
#define H2  128
#define N_EDGES 3200000

typedef __attribute__((ext_vector_type(8))) short bf16x8;
typedef __attribute__((ext_vector_type(4))) float f32x4;
typedef __attribute__((ext_vector_type(2))) float f32x2;

__device__ __forceinline__ unsigned short f2b(float x) {
  union { float f; unsigned int u; } c; c.f = x;
  unsigned int u = c.u;
  unsigned int r = (u + 0x7FFFu + ((u >> 16) & 1u)) >> 16;
  return (unsigned short)r;
}
__device__ __forceinline__ unsigned fau(float x) {
  union { float f; unsigned u; } c; c.f = x; return c.u;
}

typedef const __attribute__((address_space(1))) unsigned int* gp1_t;
typedef __attribute__((address_space(3))) unsigned int* sp3_t;
__device__ __forceinline__ void gl_lds16(const void* g, void* s) {
  __builtin_amdgcn_global_load_lds((gp1_t)g, (sp3_t)s, 16, 0, 0);
}

// ---- prep: W1[k][n] -> W1t[n][k] bf16 pre-swizzled; same for W2; zero hp ----
__global__ void prep_kernel(const float* __restrict__ W1, const float* __restrict__ W2,
                            unsigned short* __restrict__ W1t, unsigned short* __restrict__ W2t,
                            float4* __restrict__ hp4) {
  int idx = blockIdx.x * blockDim.x + threadIdx.x;
  int stride = gridDim.x * blockDim.x;
  for (int i = idx; i < H1 * NIN; i += stride) {
    int n = i >> 9, k = i & 511;
    W1t[i] = f2b(W1[(size_t)(k ^ ((n & 7) << 3)) * H1 + n]);
  }
  for (int i = idx; i < H2 * H1; i += stride) {
    int n = i >> 9, k = i & 511;
    W2t[i] = f2b(W2[(size_t)(k ^ ((n & 7) << 3)) * H2 + n]);
  }
  float4 z; z.x = 0.f; z.y = 0.f; z.z = 0.f; z.w = 0.f;
  for (int i = idx; i < (N_NODES * H2) / 4; i += stride) hp4[i] = z;
}

// ---- GEMM1: h_pre = relu(seq_a @ W1 + b1); A read f32 direct, cvt in-reg ----
__global__ __launch_bounds__(256, 3) void gemm1_kernel(
    const float* __restrict__ A, const unsigned short* __restrict__ W1t,
    const float* __restrict__ b1, unsigned short* __restrict__ h_pre)
{
  __shared__ __align__(16) float Af[128 * 64];           // 32 KB, 16B-granule swizzled
  __shared__ __align__(16) unsigned short Bsm[128 * 64]; // 16 KB
  const int tid = threadIdx.x;
  const int w = tid >> 6, lane = tid & 63;
  const int l15 = lane & 15, lg = lane >> 4;
  const int wr = w & 1, wc = w >> 1;
  const int row0 = blockIdx.y * 128;
  const int n0 = blockIdx.x * 128;

  f32x4 acc[4][4];
  #pragma unroll
  for (int m = 0; m < 4; ++m)
    #pragma unroll
    for (int n = 0; n < 4; ++n) acc[m][n] = (f32x4){0.f, 0.f, 0.f, 0.f};

  // precompute staging source bases (kt-independent)
  const char* abase[8];
  #pragma unroll
  for (int it = 0; it < 8; ++it) {
    int o = it * 4096 + tid * 16;
    int r = o >> 8, kb = o & 255;
    int kbs = kb ^ ((r & 7) << 4);          // inverse swizzle on SOURCE (rule #21)
    int rr = row0 + r; if (rr >= N_NODES) rr = N_NODES - 1;
    abase[it] = (const char*)A + ((size_t)rr << 11) + kbs;
  }
  const char* bbase[4];
  #pragma unroll
  for (int it = 0; it < 4; ++it) {
    int o = it * 4096 + tid * 16;
    int r = o >> 7, kb = o & 127;
    bbase[it] = (const char*)W1t + (((size_t)(n0 + r)) << 10) + kb;
  }

  for (int kt = 0; kt < 8; ++kt) {
    #pragma unroll
    for (int it = 0; it < 8; ++it)
      gl_lds16(abase[it] + (kt << 8), (char*)Af + it * 4096 + tid * 16);
    #pragma unroll
    for (int it = 0; it < 4; ++it)
      gl_lds16(bbase[it] + (kt << 7), (char*)Bsm + it * 4096 + tid * 16);
    __syncthreads();
    #pragma unroll
    for (int ks = 0; ks < 2; ++ks) {
      bf16x8 af[4], bfr[4];
      #pragma unroll
      for (int m = 0; m < 4; ++m) {
        int r = wr * 64 + m * 16 + l15;
        int swz = (r & 7) << 4;
        int kb = ks * 128 + lg * 32;
        const char* base = (const char*)Af + (r << 8);
        f32x4 va = *(const f32x4*)(base + (kb ^ swz));
        f32x4 vb = *(const f32x4*)(base + ((kb + 16) ^ swz));
        union { bf16x8 h; unsigned u[4]; } pk;
        pk.u[0] = __builtin_amdgcn_perm(fau(va[0]), fau(va[1]), 0x03020706u);
        pk.u[1] = __builtin_amdgcn_perm(fau(va[2]), fau(va[3]), 0x03020706u);
        pk.u[2] = __builtin_amdgcn_perm(fau(vb[0]), fau(vb[1]), 0x03020706u);
        pk.u[3] = __builtin_amdgcn_perm(fau(vb[2]), fau(vb[3]), 0x03020706u);
        af[m] = pk.h;
      }
      #pragma unroll
      for (int n = 0; n < 4; ++n) {
        int r = wc * 64 + n * 16 + l15;
        bfr[n] = *(const bf16x8*)((const char*)Bsm + (r << 7) + (((ks << 6) + (lg << 4)) ^ ((r & 7) << 4)));
      }
      #pragma unroll
      for (int m = 0; m < 4; ++m)
        #pragma unroll
        for (int n = 0; n < 4; ++n)
          acc[m][n] = __builtin_amdgcn_mfma_f32_16x16x32_bf16(af[m], bfr[n], acc[m][n], 0, 0, 0);
    }
    __syncthreads();
  }

  #pragma unroll
  for (int n = 0; n < 4; ++n) {
    int col = n0 + wc * 64 + n * 16 + l15;
    float bias = b1[col];
    #pragma unroll
    for (int m = 0; m < 4; ++m) {
      #pragma unroll
      for (int q = 0; q < 4; ++q) {
        int row = row0 + wr * 64 + m * 16 + lg * 4 + q;
        if (row < N_NODES) {
          float v = acc[m][n][q] + bias;
          v = v > 0.f ? v : 0.f;
          h_pre[((size_t)row << 9) + (col ^ ((row & 7) << 3))] = f2b(v);
        }
      }
    }
  }
}

// ---- GEMM2: ha = h_pre @ W2 + b2 -> f32 d_out + fp8 e4m3 gather table ----
__global__ __launch_bounds__(256, 4) void gemm2_kernel(
    const unsigned short* __restrict__ Hp, const unsigned short* __restrict__ W2t,
    const float* __restrict__ b2, float* __restrict__ ha_out, unsigned char* __restrict__ ha8)
{
  __shared__ __align__(16) unsigned short Asm[128 * 64];
  __shared__ __align__(16) unsigned short Bsm[128 * 64];
  const int tid = threadIdx.x;
  const int w = tid >> 6, lane = tid & 63;
  const int l15 = lane & 15, lg = lane >> 4;
  const int wr = w & 1, wc = w >> 1;
  const int row0 = blockIdx.y * 128;

  f32x4 acc[4][4];
  #pragma unroll
  for (int m = 0; m < 4; ++m)
    #pragma unroll
    for (int n = 0; n < 4; ++n) acc[m][n] = (f32x4){0.f, 0.f, 0.f, 0.f};

  const int so = w * 1024 + lane * 16;
  for (int kt = 0; kt < 8; ++kt) {
    #pragma unroll
    for (int it = 0; it < 4; ++it) {
      int o = it * 4096 + so;
      int r = o >> 7, kb = o & 127;
      gl_lds16((const char*)Hp + (((size_t)(row0 + r)) << 10) + (kt << 7) + kb, (char*)Asm + o);
      gl_lds16((const char*)W2t + (((size_t)r) << 10) + (kt << 7) + kb, (char*)Bsm + o);
    }
    __syncthreads();
    #pragma unroll
    for (int ks = 0; ks < 2; ++ks) {
      bf16x8 af[4], bfr[4];
      #pragma unroll
      for (int m = 0; m < 4; ++m) {
        int r = wr * 64 + m * 16 + l15;
        af[m] = *(const bf16x8*)((const char*)Asm + (r << 7) + (((ks << 6) + (lg << 4)) ^ ((r & 7) << 4)));
      }
      #pragma unroll
      for (int n = 0; n < 4; ++n) {
        int r = wc * 64 + n * 16 + l15;
        bfr[n] = *(const bf16x8*)((const char*)Bsm + (r << 7) + (((ks << 6) + (lg << 4)) ^ ((r & 7) << 4)));
      }
      #pragma unroll
      for (int m = 0; m < 4; ++m)
        #pragma unroll
        for (int n = 0; n < 4; ++n)
          acc[m][n] = __builtin_amdgcn_mfma_f32_16x16x32_bf16(af[m], bfr[n], acc[m][n], 0, 0, 0);
    }
    __syncthreads();
  }

  #pragma unroll
  for (int n = 0; n < 4; ++n) {
    int col = wc * 64 + n * 16 + l15;
    float bias = b2[col];
    #pragma unroll
    for (int m = 0; m < 4; ++m) {
      #pragma unroll
      for (int q = 0; q < 4; ++q) {
        int row = row0 + wr * 64 + m * 16 + lg * 4 + q;
        if (row < N_NODES) {
          float v = acc[m][n][q] + bias;
          ha_out[((size_t)row << 7) + col] = v;
          int p8 = __builtin_amdgcn_cvt_pk_fp8_f32(v, v, 0, false);
          ha8[((size_t)row << 7) + col] = (unsigned char)(p8 & 0xff);
        }
      }
    }
  }
}

// ---- aggregation v3: fp8 gather table, 8 gathers in flight, atomic-elision ----
__global__ __launch_bounds__(256) void agg_kernel(
    const int* __restrict__ rows, const int* __restrict__ cols, const float* __restrict__ vals,
    const unsigned char* __restrict__ gtab8, float* __restrict__ hp)
{
  const int lane = threadIdx.x & 63;
  const int gw = (blockIdx.x * blockDim.x + threadIdx.x) >> 6;
  const int nw = (gridDim.x * blockDim.x) >> 6;
  int epw = (N_EDGES + nw - 1) / nw;
  epw = (epw + 7) & ~7;
  int e0 = gw * epw;
  if (e0 >= N_EDGES) return;
  int e1 = e0 + epw; if (e1 > N_EDGES) e1 = N_EDGES;
  const int ef = e0 + ((e1 - e0) & ~7);

  float acc0 = 0.f, acc1 = 0.f;
  int cur = rows[e0];
  bool first = true;

  auto flushrow = [&](int rr) {
    float* p = &hp[((size_t)cur << 7) + (lane << 1)];
    if (first) { atomicAdd(p, acc0); atomicAdd(p + 1, acc1); first = false; }
    else       { float2 st; st.x = acc0; st.y = acc1; *(float2*)p = st; }
    acc0 = 0.f; acc1 = 0.f; cur = rr;
  };
  auto edge = [&](int rr, float vv, f32x2 f) {
    if (rr != cur) flushrow(rr);
    acc0 = fmaf(vv, f.x, acc0);
    acc1 = fmaf(vv, f.y, acc1);
  };

  for (int e = e0; e < ef; e += 8) {
    int4   ra = *(const int4*)(rows + e);
    int4   rb = *(const int4*)(rows + e + 4);
    int4   ca = *(const int4*)(cols + e);
    int4   cb = *(const int4*)(cols + e + 4);
    float4 va = *(const float4*)(vals + e);
    float4 vb = *(const float4*)(vals + e + 4);
    // 8 independent 2-byte gathers in flight
    unsigned short g0 = *(const unsigned short*)(gtab8 + ((size_t)ca.x << 7) + (lane << 1));
    unsigned short g1 = *(const unsigned short*)(gtab8 + ((size_t)ca.y << 7) + (lane << 1));
    unsigned short g2 = *(const unsigned short*)(gtab8 + ((size_t)ca.z << 7) + (lane << 1));
    unsigned short g3 = *(const unsigned short*)(gtab8 + ((size_t)ca.w << 7) + (lane << 1));
    unsigned short g4 = *(const unsigned short*)(gtab8 + ((size_t)cb.x << 7) + (lane << 1));
    unsigned short g5 = *(const unsigned short*)(gtab8 + ((size_t)cb.y << 7) + (lane << 1));
    unsigned short g6 = *(const unsigned short*)(gtab8 + ((size_t)cb.z << 7) + (lane << 1));
    unsigned short g7 = *(const unsigned short*)(gtab8 + ((size_t)cb.w << 7) + (lane << 1));
    f32x2 f0 = __builtin_amdgcn_cvt_pk_f32_fp8((int)g0, false);
    f32x2 f1 = __builtin_amdgcn_cvt_pk_f32_fp8((int)g1, false);
    f32x2 f2 = __builtin_amdgcn_cvt_pk_f32_fp8((int)g2, false);
    f32x2 f3 = __builtin_amdgcn_cvt_pk_f32_fp8((int)g3, false);
    f32x2 f4 = __builtin_amdgcn_cvt_pk_f32_fp8((int)g4, false);
    f32x2 f5 = __builtin_amdgcn_cvt_pk_f32_fp8((int)g5, false);
    f32x2 f6 = __builtin_amdgcn_cvt_pk_f32_fp8((int)g6, false);
    f32x2 f7 = __builtin_amdgcn_cvt_pk_f32_fp8((int)g7, false);
    if ((ra.x == cur) && (rb.w == cur)) {
      float p0 = fmaf(va.x, f0.x, fmaf(va.z, f2.x, fmaf(vb.x, f4.x, fmaf(vb.z, f6.x, acc0))));
      float q0 = fmaf(va.y, f1.x, fmaf(va.w, f3.x, fmaf(vb.y, f5.x, fmaf(vb.w, f7.x, 0.f))));
      acc0 = p0 + q0;
      float p1 = fmaf(va.x, f0.y, fmaf(va.z, f2.y, fmaf(vb.x, f4.y, fmaf(vb.z, f6.y, acc1))));
      float q1 = fmaf(va.y, f1.y, fmaf(va.w, f3.y, fmaf(vb.y, f5.y, fmaf(vb.w, f7.y, 0.f))));
      acc1 = p1 + q1;
    } else {
      edge(ra.x, va.x, f0); edge(ra.y, va.y, f1);
      edge(ra.z, va.z, f2); edge(ra.w, va.w, f3);
      edge(rb.x, vb.x, f4); edge(rb.y, vb.y, f5);
      edge(rb.z, vb.z, f6); edge(rb.w, vb.w, f7);
    }
  }
  for (int e = ef; e < e1; ++e) {
    unsigned short g = *(const unsigned short*)(gtab8 + ((size_t)cols[e] << 7) + (lane << 1));
    f32x2 f = __builtin_amdgcn_cvt_pk_f32_fp8((int)g, false);
    edge(rows[e], vals[e], f);
  }
  atomicAdd(&hp[((size_t)cur << 7) + (lane << 1)], acc0);
  atomicAdd(&hp[((size_t)cur << 7) + (lane << 1) + 1], acc1);
}

extern "C" void kernel_launch(void* const* d_in, const int* in_sizes, int n_in,
                              void* d_out, int out_size, void* d_ws, size_t ws_size,
                              hipStream_t stream) {
  const float* seq_a    = (const float*)d_in[0];
  const float* W1       = (const float*)d_in[1];
  const float* b1       = (const float*)d_in[2];
  const float* W2       = (const float*)d_in[3];
  const float* b2       = (const float*)d_in[4];
  const int*   adj_rows = (const int*)d_in[5];
  const int*   adj_cols = (const int*)d_in[6];
  const float* adj_vals = (const float*)d_in[7];

  unsigned short* h_pre = (unsigned short*)d_ws;            // ROWS_PAD x 512 bf16 (swizzled)
  unsigned short* W1t   = h_pre + (size_t)ROWS_PAD * H1;    // 512 x 512 bf16
  unsigned short* W2t   = W1t + (size_t)H1 * NIN;           // 128 x 512 bf16
  unsigned char*  ha8   = (unsigned char*)(W2t + (size_t)H2 * H1);  // N_NODES x 128 fp8

  float* ha_out = (float*)d_out;
  float* hp     = ha_out + (size_t)N_NODES * H2;

  prep_kernel<<<1280, 256, 0, stream>>>(W1, W2, W1t, W2t, (float4*)hp);
  gemm1_kernel<<<dim3(4, 782), 256, 0, stream>>>(seq_a, W1t, b1, h_pre);
  gemm2_kernel<<<dim3(1, 782), 256, 0, stream>>>(h_pre, W2t, b2, ha_out, ha8);
  agg_kernel<<<2048, 256, 0, stream>>>(adj_rows, adj_cols, adj_vals, ha8, hp);
}